// Round 8
// baseline (534.810 us; speedup 1.0000x reference)
//
#include <hip/hip_runtime.h>
#include <hip/hip_bf16.h>
#include <stdint.h>

#define D_DIM 1024
#define P_ROWS 8192
#define K_ROWS 131072
#define M_DIM 512
#define L_STEPS 64
#define BM 64
#define XS_ROW_BYTES 4096

typedef short bf16x8_t __attribute__((ext_vector_type(8)));
typedef float f32x4_t __attribute__((ext_vector_type(4)));

typedef const __attribute__((address_space(1))) void* gas_t;
typedef __attribute__((address_space(3))) void* las_t;

__device__ __forceinline__ uint32_t f2bf(float f) {
  union { float f; uint32_t u; } c; c.f = f;
  const uint32_t u = c.u;
  return (u + 0x7FFFu + ((u >> 16) & 1u)) >> 16;   // RNE
}

__device__ __forceinline__ bf16x8_t as_bf16x8(uint4 v) {
  union { uint4 u; bf16x8_t h; } c; c.u = v; return c.h;
}

__device__ __forceinline__ bf16x8_t cvt_frag(const f32x4_t& a0, const f32x4_t& a1) {
  uint32_t p0, p1, p2, p3;
  asm("v_cvt_pk_bf16_f32 %0, %1, %2" : "=v"(p0) : "v"(a0[0]), "v"(a0[1]));
  asm("v_cvt_pk_bf16_f32 %0, %1, %2" : "=v"(p1) : "v"(a0[2]), "v"(a0[3]));
  asm("v_cvt_pk_bf16_f32 %0, %1, %2" : "=v"(p2) : "v"(a1[0]), "v"(a1[1]));
  asm("v_cvt_pk_bf16_f32 %0, %1, %2" : "=v"(p3) : "v"(a1[2]), "v"(a1[3]));
  union { uint32_t u[4]; bf16x8_t h; } c;
  c.u[0] = p0; c.u[1] = p1; c.u[2] = p2; c.u[3] = p3;
  return c.h;
}

// v[d] += sum_i y[i] * X[i,d]
__global__ void xty_kernel(const float* __restrict__ X, const float* __restrict__ y,
                           float* __restrict__ v) {
  const int d0 = threadIdx.x * 4;
  float a0 = 0.f, a1 = 0.f, a2 = 0.f, a3 = 0.f;
  for (int i = blockIdx.x; i < P_ROWS; i += gridDim.x) {
    const float s = y[i];
    const float4 x = *reinterpret_cast<const float4*>(X + (size_t)i * D_DIM + d0);
    a0 += s * x.x; a1 += s * x.y; a2 += s * x.z; a3 += s * x.w;
  }
  atomicAdd(v + d0 + 0, a0);
  atomicAdd(v + d0 + 1, a1);
  atomicAdd(v + d0 + 2, a2);
  atomicAdd(v + d0 + 3, a3);
}

// wout[d] += sum_i (X[i,:].win) * X[i,d]
__global__ void xtxw_kernel(const float* __restrict__ X, const float* __restrict__ win,
                            float* __restrict__ wout) {
  __shared__ float red[4][D_DIM];
  const int lane = threadIdx.x & 63;
  const int wave = threadIdx.x >> 6;
  const int gw = blockIdx.x * 4 + wave;
  const int nw = gridDim.x * 4;
  float wv[16], acc[16];
#pragma unroll
  for (int q = 0; q < 4; ++q) {
    const float4 tv = *reinterpret_cast<const float4*>(win + q * 256 + lane * 4);
    wv[q*4+0] = tv.x; wv[q*4+1] = tv.y; wv[q*4+2] = tv.z; wv[q*4+3] = tv.w;
  }
#pragma unroll
  for (int j = 0; j < 16; ++j) acc[j] = 0.f;
  for (int i = gw; i < P_ROWS; i += nw) {
    const float* xr = X + (size_t)i * D_DIM;
    float xv[16];
    float dot = 0.f;
#pragma unroll
    for (int q = 0; q < 4; ++q) {
      const float4 tv = *reinterpret_cast<const float4*>(xr + q * 256 + lane * 4);
      xv[q*4+0] = tv.x; xv[q*4+1] = tv.y; xv[q*4+2] = tv.z; xv[q*4+3] = tv.w;
      dot += tv.x * wv[q*4+0] + tv.y * wv[q*4+1] + tv.z * wv[q*4+2] + tv.w * wv[q*4+3];
    }
#pragma unroll
    for (int m = 1; m < 64; m <<= 1) dot += __shfl_xor(dot, m);
#pragma unroll
    for (int j = 0; j < 16; ++j) acc[j] += dot * xv[j];
  }
#pragma unroll
  for (int q = 0; q < 4; ++q) {
    float4 tv;
    tv.x = acc[q*4+0]; tv.y = acc[q*4+1]; tv.z = acc[q*4+2]; tv.w = acc[q*4+3];
    *reinterpret_cast<float4*>(&red[wave][q * 256 + lane * 4]) = tv;
  }
  __syncthreads();
  const int d0 = threadIdx.x * 4;
#pragma unroll
  for (int j = 0; j < 4; ++j)
    atomicAdd(wout + d0 + j, red[0][d0+j] + red[1][d0+j] + red[2][d0+j] + red[3][d0+j]);
}

// rep = gamma*(64 v - 2016 eps u1/P + 41664 eps^2 u2/P^2); emit rep/(L*P) and rep/||rep||
__global__ void combine_kernel(const float* __restrict__ v, const float* __restrict__ u1,
                               const float* __restrict__ u2, const float* __restrict__ gamma_p,
                               float* __restrict__ rep_lin, float* __restrict__ repn) {
  __shared__ float sred[4];
  const float gamma = *gamma_p;
  const float eps = gamma / (float)L_STEPS;
  const float c1 = 2016.0f * eps / (float)P_ROWS;
  const float c2 = 41664.0f * eps * eps / ((float)P_ROWS * (float)P_ROWS);
  const int d0 = threadIdx.x * 4;
  float r[4];
  float ss = 0.f;
#pragma unroll
  for (int j = 0; j < 4; ++j) {
    const float val = gamma * ((float)L_STEPS * v[d0+j] - c1 * u1[d0+j] + c2 * u2[d0+j]);
    r[j] = val;
    ss += val * val;
  }
#pragma unroll
  for (int m = 1; m < 64; m <<= 1) ss += __shfl_xor(ss, m);
  if ((threadIdx.x & 63) == 0) sred[threadIdx.x >> 6] = ss;
  __syncthreads();
  const float norm = sqrtf(sred[0] + sred[1] + sred[2] + sred[3]);
  const float inv_norm = 1.0f / (norm + 1e-8f);
  const float lin_s = 1.0f / ((float)L_STEPS * (float)P_ROWS);
#pragma unroll
  for (int j = 0; j < 4; ++j) {
    rep_lin[d0+j] = r[j] * lin_s;
    repn[d0+j]    = r[j] * inv_norm;
  }
}

// WnF fragment-major: byte addr (s*32+f)*1024 + l*16 holds bf16 x8 of
// W[f*16+(l&15)][s*32+(l>>4)*8 + 0..7] * repn[...]
__global__ void wn_frag_kernel(const float* __restrict__ W, const float* __restrict__ repn,
                               ushort* __restrict__ WnF) {
  const int gid = blockIdx.x * 256 + threadIdx.x;   // 65536
  const int l = gid & 63;
  const int f = (gid >> 6) & 31;
  const int s = gid >> 11;
  const int m = f * 16 + (l & 15);
  const int d0 = s * 32 + ((l >> 4) << 3);
  const float4 w0 = *reinterpret_cast<const float4*>(W + (size_t)m * D_DIM + d0);
  const float4 w1 = *reinterpret_cast<const float4*>(W + (size_t)m * D_DIM + d0 + 4);
  const float4 r0 = *reinterpret_cast<const float4*>(repn + d0);
  const float4 r1 = *reinterpret_cast<const float4*>(repn + d0 + 4);
  uint4 o;
  o.x = f2bf(w0.x*r0.x) | (f2bf(w0.y*r0.y) << 16);
  o.y = f2bf(w0.z*r0.z) | (f2bf(w0.w*r0.w) << 16);
  o.z = f2bf(w1.x*r1.x) | (f2bf(w1.y*r1.y) << 16);
  o.w = f2bf(w1.z*r1.z) | (f2bf(w1.w*r1.w) << 16);
  *reinterpret_cast<uint4*>(WnF + (size_t)gid * 8) = o;
}

// Fused GEMM. BM=64, BN=512(full), 256 threads = 4 waves, wave tile 64x128,
// BK=32, 32 steps, 2 blocks/CU.
// A: f32 via global_load_lds, 4 x 8KB ring, depth-3, swizzled (conflict-free).
// B: fragment-major bf16, REGISTER double-buffered depth-1 prefetch: B(s+1)
//    issued at top of step s, so its L2 latency spans the whole step.
// Exact counted vmcnt before MFMA retires B(s) (and, in-order, DMA(s+1))
// while leaving B(s+1)x8 + 2 A-DMAs in flight across the raw s_barrier:
//   newer-than-B(s) = DMA(s+2)x2 + B(s+1)x8 + DMA(s+3)x2 = 12  (tail: 10/8/0).
#define STEP(SC, BC, BN, DO_STAGE, DO_PF, WSTR) do {                             \
    if (DO_PF) {                                                                 \
      _Pragma("unroll")                                                          \
      for (int ni = 0; ni < 8; ++ni)                                             \
        BN[ni] = *reinterpret_cast<const uint4*>(gB + (size_t)((SC) + 1) * 32768 + ni * 1024); \
    }                                                                            \
    if (DO_STAGE) stage((SC) + 3);                                               \
    const char* Ab = &Abuf[0][0] + ((SC) & 3) * 8192;                            \
    f32x4_t va[4], vb[4];                                                        \
    _Pragma("unroll")                                                            \
    for (int mi = 0; mi < 4; ++mi) {                                             \
      va[mi] = *reinterpret_cast<const f32x4_t*>(Ab + aoff0 + mi * 2048);        \
      vb[mi] = *reinterpret_cast<const f32x4_t*>(Ab + aoff1 + mi * 2048);        \
    }                                                                            \
    if (wn == 0) {                                                               \
      const f32x4_t rp0 = *reinterpret_cast<const f32x4_t*>((const char*)repl + (SC) * 128 + roff);      \
      const f32x4_t rp1 = *reinterpret_cast<const f32x4_t*>((const char*)repl + (SC) * 128 + roff + 16); \
      _Pragma("unroll")                                                          \
      for (int mi = 0; mi < 4; ++mi)                                             \
        lin[mi] += va[mi][0]*rp0[0] + va[mi][1]*rp0[1] + va[mi][2]*rp0[2] + va[mi][3]*rp0[3]  \
                 + vb[mi][0]*rp1[0] + vb[mi][1]*rp1[1] + vb[mi][2]*rp1[2] + vb[mi][3]*rp1[3]; \
    }                                                                            \
    bf16x8_t afr[4];                                                             \
    _Pragma("unroll")                                                            \
    for (int mi = 0; mi < 4; ++mi) afr[mi] = cvt_frag(va[mi], vb[mi]);           \
    __builtin_amdgcn_sched_barrier(0);                                           \
    asm volatile(WSTR ::: "memory");                                             \
    __builtin_amdgcn_sched_barrier(0);                                           \
    __builtin_amdgcn_s_setprio(1);                                               \
    _Pragma("unroll")                                                            \
    for (int mi = 0; mi < 4; ++mi)                                               \
      _Pragma("unroll")                                                          \
      for (int ni = 0; ni < 8; ++ni)                                             \
        acc[mi][ni] = __builtin_amdgcn_mfma_f32_16x16x32_bf16(afr[mi], as_bf16x8(BC[ni]), acc[mi][ni], 0, 0, 0); \
    __builtin_amdgcn_s_setprio(0);                                               \
    __builtin_amdgcn_sched_barrier(0);                                           \
    __builtin_amdgcn_s_barrier();                                                \
    __builtin_amdgcn_sched_barrier(0);                                           \
  } while (0)

__global__ __launch_bounds__(256, 2)
void fused_kernel(const float* __restrict__ Xs, const ushort* __restrict__ WnF,
                  const float* __restrict__ rep_lin, const float* __restrict__ b1,
                  const float* __restrict__ aw, const float* __restrict__ b2p,
                  float* __restrict__ out) {
  __shared__ __align__(16) char Abuf[4][8192];     // 32 KB, f32 A tiles (swizzled)
  __shared__ __align__(16) float repl[D_DIM];      // 4 KB
  __shared__ float mlp_acc[BM];
  __shared__ float lin_acc[BM];

  const int t = threadIdx.x;
  const int lane = t & 63;
  const int wn = t >> 6;       // 0..3 (wave id == N-slice)
  const int fr = lane & 15;
  const int kg = lane >> 4;
  const size_t blockRow = (size_t)blockIdx.x * BM;

  // --- DMA staging: lane-linear LDS dst, pre-swizzled global src ---
  const int sr0 = wn * 16 + (lane >> 3);           // rows 0..63
  const int sr1 = sr0 + 8;
  const char* gA0 = (const char*)Xs + (blockRow + (size_t)sr0) * XS_ROW_BYTES
                  + (size_t)(((lane & 7) ^ (sr0 & 7)) * 16);
  const char* gA1 = (const char*)Xs + (blockRow + (size_t)sr1) * XS_ROW_BYTES
                  + (size_t)(((lane & 7) ^ (sr1 & 7)) * 16);

  const char* gB = (const char*)WnF + (size_t)wn * 8192 + (size_t)lane * 16;

  // --- swizzled ds_read offsets for A frags (row = fr + mi*16) ---
  const int fs = fr & 7;
  const int aoff0 = fr * 128 + (((kg * 2)     ^ fs) * 16);   // + mi*2048
  const int aoff1 = fr * 128 + (((kg * 2 + 1) ^ fs) * 16);
  const int roff = kg * 32;                                  // + s*128

  auto stage = [&](int tile) {
    char* d0 = &Abuf[0][0] + (size_t)((tile & 3) * 8192 + wn * 2048);
    __builtin_amdgcn_global_load_lds((gas_t)(gA0 + (size_t)tile * 128), (las_t)d0, 16, 0, 0);
    __builtin_amdgcn_global_load_lds((gas_t)(gA1 + (size_t)tile * 128), (las_t)(d0 + 1024), 16, 0, 0);
  };

  f32x4_t acc[4][8];
#pragma unroll
  for (int mi = 0; mi < 4; ++mi)
#pragma unroll
    for (int ni = 0; ni < 8; ++ni)
      acc[mi][ni] = f32x4_t{0.f, 0.f, 0.f, 0.f};
  float lin[4] = {0.f, 0.f, 0.f, 0.f};
  uint4 B0[8], B1[8];

  // ---- prologue: A(0..2) DMA, B(0) -> B0 ----
  if (t < BM) mlp_acc[t] = 0.f;
  *reinterpret_cast<float4*>(&repl[t * 4]) = *reinterpret_cast<const float4*>(rep_lin + t * 4);
  stage(0); stage(1); stage(2);
#pragma unroll
  for (int ni = 0; ni < 8; ++ni)
    B0[ni] = *reinterpret_cast<const uint4*>(gB + ni * 1024);
  asm volatile("s_waitcnt vmcnt(0)" ::: "memory");
  __syncthreads();

  // ---- main loop: s = 0..28 full pipeline ----
  for (int su = 0; su < 14; ++su) {
    STEP(2 * su,     B0, B1, 1, 1, "s_waitcnt vmcnt(12)");
    STEP(2 * su + 1, B1, B0, 1, 1, "s_waitcnt vmcnt(12)");
  }
  STEP(28, B0, B1, 1, 1, "s_waitcnt vmcnt(12)");
  // ---- tail: exact counts as staging/prefetch taper ----
  STEP(29, B1, B0, 0, 1, "s_waitcnt vmcnt(10)");
  STEP(30, B0, B1, 0, 1, "s_waitcnt vmcnt(8)");
  STEP(31, B1, B0, 0, 0, "s_waitcnt vmcnt(0)");

  // ---- epilogue ----
  float b1r[8], ar[8];
#pragma unroll
  for (int ni = 0; ni < 8; ++ni) {
    const int c = wn * 128 + ni * 16 + fr;
    b1r[ni] = b1[c];
    ar[ni]  = aw[c];
  }
#pragma unroll
  for (int mi = 0; mi < 4; ++mi) {
#pragma unroll
    for (int r = 0; r < 4; ++r) {
      float sum = 0.f;
#pragma unroll
      for (int ni = 0; ni < 8; ++ni) {
        const float h = acc[mi][ni][r] + b1r[ni];
        sum += fmaxf(h, 0.f) * ar[ni];
      }
      sum += __shfl_xor(sum, 1);
      sum += __shfl_xor(sum, 2);
      sum += __shfl_xor(sum, 4);
      sum += __shfl_xor(sum, 8);
      if (fr == 0) {
        const int row = mi * 16 + kg * 4 + r;
        atomicAdd(&mlp_acc[row], sum);
      }
    }
  }
  if (wn == 0) {
#pragma unroll
    for (int mi = 0; mi < 4; ++mi) {
      lin[mi] += __shfl_xor(lin[mi], 16);
      lin[mi] += __shfl_xor(lin[mi], 32);
    }
    if (lane < 16) {
#pragma unroll
      for (int mi = 0; mi < 4; ++mi)
        lin_acc[mi * 16 + lane] = lin[mi];
    }
  }
  __syncthreads();
  if (t < BM)
    out[blockRow + t] = lin_acc[t] + mlp_acc[t] + b2p[0];
}

extern "C" void kernel_launch(void* const* d_in, const int* in_sizes, int n_in,
                              void* d_out, int out_size, void* d_ws, size_t ws_size,
                              hipStream_t stream) {
  const float* X     = (const float*)d_in[0];
  const float* y     = (const float*)d_in[1];
  const float* Xs    = (const float*)d_in[2];
  const float* gamma = (const float*)d_in[3];
  const float* W     = (const float*)d_in[4];
  const float* a     = (const float*)d_in[5];
  const float* b1    = (const float*)d_in[6];
  const float* b2    = (const float*)d_in[7];
  float* out = (float*)d_out;

  char* ws = (char*)d_ws;
  float*  v       = (float*)(ws + 0);
  float*  u1      = (float*)(ws + 4096);
  float*  u2      = (float*)(ws + 8192);
  float*  rep_lin = (float*)(ws + 12288);
  float*  repn    = (float*)(ws + 16384);
  ushort* WnF     = (ushort*)(ws + 20480);

  hipMemsetAsync(ws, 0, 3 * 4096, stream);
  hipLaunchKernelGGL(xty_kernel,     dim3(1024), dim3(256), 0, stream, X, y, v);
  hipLaunchKernelGGL(xtxw_kernel,    dim3(512),  dim3(256), 0, stream, X, v, u1);
  hipLaunchKernelGGL(xtxw_kernel,    dim3(512),  dim3(256), 0, stream, X, u1, u2);
  hipLaunchKernelGGL(combine_kernel, dim3(1),    dim3(256), 0, stream, v, u1, u2, gamma, rep_lin, repn);
  hipLaunchKernelGGL(wn_frag_kernel, dim3(256),  dim3(256), 0, stream, W, repn, WnF);
  hipLaunchKernelGGL(fused_kernel,   dim3(K_ROWS / BM), dim3(256), 0, stream,
                     Xs, WnF, rep_lin, b1, a, b2, out);
}

// Round 10
// 322.155 us; speedup vs baseline: 1.6601x; 1.6601x over previous
//
#include <hip/hip_runtime.h>
#include <hip/hip_bf16.h>
#include <stdint.h>

#define D_DIM 1024
#define P_ROWS 8192
#define K_ROWS 131072
#define M_DIM 512
#define L_STEPS 64
#define BM 64
#define XS_ROW_BYTES 4096

typedef short bf16x8_t __attribute__((ext_vector_type(8)));
typedef float f32x4_t __attribute__((ext_vector_type(4)));

typedef const __attribute__((address_space(1))) void* gas_t;
typedef __attribute__((address_space(3))) void* las_t;

__device__ __forceinline__ uint32_t f2bf(float f) {
  union { float f; uint32_t u; } c; c.f = f;
  const uint32_t u = c.u;
  return (u + 0x7FFFu + ((u >> 16) & 1u)) >> 16;   // RNE
}

__device__ __forceinline__ bf16x8_t as_bf16x8(uint4 v) {
  union { uint4 u; bf16x8_t h; } c; c.u = v; return c.h;
}

__device__ __forceinline__ bf16x8_t cvt_frag(const f32x4_t& a0, const f32x4_t& a1) {
  uint32_t p0, p1, p2, p3;
  asm("v_cvt_pk_bf16_f32 %0, %1, %2" : "=v"(p0) : "v"(a0[0]), "v"(a0[1]));
  asm("v_cvt_pk_bf16_f32 %0, %1, %2" : "=v"(p1) : "v"(a0[2]), "v"(a0[3]));
  asm("v_cvt_pk_bf16_f32 %0, %1, %2" : "=v"(p2) : "v"(a1[0]), "v"(a1[1]));
  asm("v_cvt_pk_bf16_f32 %0, %1, %2" : "=v"(p3) : "v"(a1[2]), "v"(a1[3]));
  union { uint32_t u[4]; bf16x8_t h; } c;
  c.u[0] = p0; c.u[1] = p1; c.u[2] = p2; c.u[3] = p3;
  return c.h;
}

// v[d] += sum_i y[i] * X[i,d]
__global__ void xty_kernel(const float* __restrict__ X, const float* __restrict__ y,
                           float* __restrict__ v) {
  const int d0 = threadIdx.x * 4;
  float a0 = 0.f, a1 = 0.f, a2 = 0.f, a3 = 0.f;
  for (int i = blockIdx.x; i < P_ROWS; i += gridDim.x) {
    const float s = y[i];
    const float4 x = *reinterpret_cast<const float4*>(X + (size_t)i * D_DIM + d0);
    a0 += s * x.x; a1 += s * x.y; a2 += s * x.z; a3 += s * x.w;
  }
  atomicAdd(v + d0 + 0, a0);
  atomicAdd(v + d0 + 1, a1);
  atomicAdd(v + d0 + 2, a2);
  atomicAdd(v + d0 + 3, a3);
}

// wout[d] += sum_i (X[i,:].win) * X[i,d]
__global__ void xtxw_kernel(const float* __restrict__ X, const float* __restrict__ win,
                            float* __restrict__ wout) {
  __shared__ float red[4][D_DIM];
  const int lane = threadIdx.x & 63;
  const int wave = threadIdx.x >> 6;
  const int gw = blockIdx.x * 4 + wave;
  const int nw = gridDim.x * 4;
  float wv[16], acc[16];
#pragma unroll
  for (int q = 0; q < 4; ++q) {
    const float4 tv = *reinterpret_cast<const float4*>(win + q * 256 + lane * 4);
    wv[q*4+0] = tv.x; wv[q*4+1] = tv.y; wv[q*4+2] = tv.z; wv[q*4+3] = tv.w;
  }
#pragma unroll
  for (int j = 0; j < 16; ++j) acc[j] = 0.f;
  for (int i = gw; i < P_ROWS; i += nw) {
    const float* xr = X + (size_t)i * D_DIM;
    float xv[16];
    float dot = 0.f;
#pragma unroll
    for (int q = 0; q < 4; ++q) {
      const float4 tv = *reinterpret_cast<const float4*>(xr + q * 256 + lane * 4);
      xv[q*4+0] = tv.x; xv[q*4+1] = tv.y; xv[q*4+2] = tv.z; xv[q*4+3] = tv.w;
      dot += tv.x * wv[q*4+0] + tv.y * wv[q*4+1] + tv.z * wv[q*4+2] + tv.w * wv[q*4+3];
    }
#pragma unroll
    for (int m = 1; m < 64; m <<= 1) dot += __shfl_xor(dot, m);
#pragma unroll
    for (int j = 0; j < 16; ++j) acc[j] += dot * xv[j];
  }
#pragma unroll
  for (int q = 0; q < 4; ++q) {
    float4 tv;
    tv.x = acc[q*4+0]; tv.y = acc[q*4+1]; tv.z = acc[q*4+2]; tv.w = acc[q*4+3];
    *reinterpret_cast<float4*>(&red[wave][q * 256 + lane * 4]) = tv;
  }
  __syncthreads();
  const int d0 = threadIdx.x * 4;
#pragma unroll
  for (int j = 0; j < 4; ++j)
    atomicAdd(wout + d0 + j, red[0][d0+j] + red[1][d0+j] + red[2][d0+j] + red[3][d0+j]);
}

// rep = gamma*(64 v - 2016 eps u1/P + 41664 eps^2 u2/P^2); emit rep/(L*P) and rep/||rep||
__global__ void combine_kernel(const float* __restrict__ v, const float* __restrict__ u1,
                               const float* __restrict__ u2, const float* __restrict__ gamma_p,
                               float* __restrict__ rep_lin, float* __restrict__ repn) {
  __shared__ float sred[4];
  const float gamma = *gamma_p;
  const float eps = gamma / (float)L_STEPS;
  const float c1 = 2016.0f * eps / (float)P_ROWS;
  const float c2 = 41664.0f * eps * eps / ((float)P_ROWS * (float)P_ROWS);
  const int d0 = threadIdx.x * 4;
  float r[4];
  float ss = 0.f;
#pragma unroll
  for (int j = 0; j < 4; ++j) {
    const float val = gamma * ((float)L_STEPS * v[d0+j] - c1 * u1[d0+j] + c2 * u2[d0+j]);
    r[j] = val;
    ss += val * val;
  }
#pragma unroll
  for (int m = 1; m < 64; m <<= 1) ss += __shfl_xor(ss, m);
  if ((threadIdx.x & 63) == 0) sred[threadIdx.x >> 6] = ss;
  __syncthreads();
  const float norm = sqrtf(sred[0] + sred[1] + sred[2] + sred[3]);
  const float inv_norm = 1.0f / (norm + 1e-8f);
  const float lin_s = 1.0f / ((float)L_STEPS * (float)P_ROWS);
#pragma unroll
  for (int j = 0; j < 4; ++j) {
    rep_lin[d0+j] = r[j] * lin_s;
    repn[d0+j]    = r[j] * inv_norm;
  }
}

// WnF fragment-major: byte addr (s*32+f)*1024 + l*16 holds bf16 x8 of
// W[f*16+(l&15)][s*32+(l>>4)*8 + 0..7] * repn[...]
__global__ void wn_frag_kernel(const float* __restrict__ W, const float* __restrict__ repn,
                               ushort* __restrict__ WnF) {
  const int gid = blockIdx.x * 256 + threadIdx.x;   // 65536
  const int l = gid & 63;
  const int f = (gid >> 6) & 31;
  const int s = gid >> 11;
  const int m = f * 16 + (l & 15);
  const int d0 = s * 32 + ((l >> 4) << 3);
  const float4 w0 = *reinterpret_cast<const float4*>(W + (size_t)m * D_DIM + d0);
  const float4 w1 = *reinterpret_cast<const float4*>(W + (size_t)m * D_DIM + d0 + 4);
  const float4 r0 = *reinterpret_cast<const float4*>(repn + d0);
  const float4 r1 = *reinterpret_cast<const float4*>(repn + d0 + 4);
  uint4 o;
  o.x = f2bf(w0.x*r0.x) | (f2bf(w0.y*r0.y) << 16);
  o.y = f2bf(w0.z*r0.z) | (f2bf(w0.w*r0.w) << 16);
  o.z = f2bf(w1.x*r1.x) | (f2bf(w1.y*r1.y) << 16);
  o.w = f2bf(w1.z*r1.z) | (f2bf(w1.w*r1.w) << 16);
  *reinterpret_cast<uint4*>(WnF + (size_t)gid * 8) = o;
}

// Fused GEMM. BM=64, BN=512(full), 256 threads = 4 waves, wave tile 64x128,
// BK=32, 32 steps, 2 blocks/CU. Unified-RF budget: acc=128 AGPR, so VGPRs
// must stay < 128 (round-8 lesson). B prefetch with ZERO extra registers:
// B(s+1) is loaded into the SAME 8 regs after the MFMA cluster (B(s) dead),
// before s_barrier -> its L2 latency spans barrier + next step's A-phase.
// vmcnt at step s: newer-than-B(s) = stage(s+3)x2 -> vmcnt(2) (tail 0).
#define STEP(SC, DO_STAGE, DO_PFB, WSTR) do {                                    \
    if (DO_STAGE) stage((SC) + 3);                                               \
    const char* Ab = &Abuf[0][0] + ((SC) & 3) * 8192;                            \
    bf16x8_t afr[4];                                                             \
    _Pragma("unroll")                                                            \
    for (int mi = 0; mi < 4; ++mi) {                                             \
      const f32x4_t va = *reinterpret_cast<const f32x4_t*>(Ab + aoff0 + mi * 2048); \
      const f32x4_t vb = *reinterpret_cast<const f32x4_t*>(Ab + aoff1 + mi * 2048); \
      if (wn == 0) {                                                             \
        const f32x4_t rp0 = *reinterpret_cast<const f32x4_t*>((const char*)repl + (SC) * 128 + roff);      \
        const f32x4_t rp1 = *reinterpret_cast<const f32x4_t*>((const char*)repl + (SC) * 128 + roff + 16); \
        lin[mi] += va[0]*rp0[0] + va[1]*rp0[1] + va[2]*rp0[2] + va[3]*rp0[3]     \
                 + vb[0]*rp1[0] + vb[1]*rp1[1] + vb[2]*rp1[2] + vb[3]*rp1[3];    \
      }                                                                          \
      afr[mi] = cvt_frag(va, vb);                                                \
    }                                                                            \
    __builtin_amdgcn_sched_barrier(0);                                           \
    asm volatile(WSTR ::: "memory");                                             \
    __builtin_amdgcn_sched_barrier(0);                                           \
    __builtin_amdgcn_s_setprio(1);                                               \
    _Pragma("unroll")                                                            \
    for (int mi = 0; mi < 4; ++mi)                                               \
      _Pragma("unroll")                                                          \
      for (int ni = 0; ni < 8; ++ni)                                             \
        acc[mi][ni] = __builtin_amdgcn_mfma_f32_16x16x32_bf16(afr[mi], as_bf16x8(Bv[ni]), acc[mi][ni], 0, 0, 0); \
    __builtin_amdgcn_s_setprio(0);                                               \
    __builtin_amdgcn_sched_barrier(0);                                           \
    if (DO_PFB) {                                                                \
      _Pragma("unroll")                                                          \
      for (int ni = 0; ni < 8; ++ni)                                             \
        Bv[ni] = *reinterpret_cast<const uint4*>(gB + (size_t)((SC) + 1) * 32768 + ni * 1024); \
    }                                                                            \
    __builtin_amdgcn_sched_barrier(0);                                           \
    __builtin_amdgcn_s_barrier();                                                \
    __builtin_amdgcn_sched_barrier(0);                                           \
  } while (0)

__global__ __launch_bounds__(256, 2)
void fused_kernel(const float* __restrict__ Xs, const ushort* __restrict__ WnF,
                  const float* __restrict__ rep_lin, const float* __restrict__ b1,
                  const float* __restrict__ aw, const float* __restrict__ b2p,
                  float* __restrict__ out) {
  __shared__ __align__(16) char Abuf[4][8192];     // 32 KB, f32 A tiles (swizzled)
  __shared__ __align__(16) float repl[D_DIM];      // 4 KB
  __shared__ float mlp_acc[BM];
  __shared__ float lin_acc[BM];

  const int t = threadIdx.x;
  const int lane = t & 63;
  const int wn = t >> 6;       // 0..3 (wave id == N-slice)
  const int fr = lane & 15;
  const int kg = lane >> 4;
  const size_t blockRow = (size_t)blockIdx.x * BM;

  // --- DMA staging: lane-linear LDS dst, pre-swizzled global src ---
  const int sr0 = wn * 16 + (lane >> 3);           // rows 0..63
  const int sr1 = sr0 + 8;
  const char* gA0 = (const char*)Xs + (blockRow + (size_t)sr0) * XS_ROW_BYTES
                  + (size_t)(((lane & 7) ^ (sr0 & 7)) * 16);
  const char* gA1 = (const char*)Xs + (blockRow + (size_t)sr1) * XS_ROW_BYTES
                  + (size_t)(((lane & 7) ^ (sr1 & 7)) * 16);

  const char* gB = (const char*)WnF + (size_t)wn * 8192 + (size_t)lane * 16;

  // --- swizzled ds_read offsets for A frags (row = fr + mi*16) ---
  const int fs = fr & 7;
  const int aoff0 = fr * 128 + (((kg * 2)     ^ fs) * 16);   // + mi*2048
  const int aoff1 = fr * 128 + (((kg * 2 + 1) ^ fs) * 16);
  const int roff = kg * 32;                                  // + s*128

  auto stage = [&](int tile) {
    char* d0 = &Abuf[0][0] + (size_t)((tile & 3) * 8192 + wn * 2048);
    __builtin_amdgcn_global_load_lds((gas_t)(gA0 + (size_t)tile * 128), (las_t)d0, 16, 0, 0);
    __builtin_amdgcn_global_load_lds((gas_t)(gA1 + (size_t)tile * 128), (las_t)(d0 + 1024), 16, 0, 0);
  };

  f32x4_t acc[4][8];
#pragma unroll
  for (int mi = 0; mi < 4; ++mi)
#pragma unroll
    for (int ni = 0; ni < 8; ++ni)
      acc[mi][ni] = f32x4_t{0.f, 0.f, 0.f, 0.f};
  float lin[4] = {0.f, 0.f, 0.f, 0.f};
  uint4 Bv[8];

  // ---- prologue: A(0..2) DMA, B(0) ----
  if (t < BM) mlp_acc[t] = 0.f;
  *reinterpret_cast<float4*>(&repl[t * 4]) = *reinterpret_cast<const float4*>(rep_lin + t * 4);
  stage(0); stage(1); stage(2);
#pragma unroll
  for (int ni = 0; ni < 8; ++ni)
    Bv[ni] = *reinterpret_cast<const uint4*>(gB + ni * 1024);
  asm volatile("s_waitcnt vmcnt(0)" ::: "memory");
  __syncthreads();

  // ---- main loop: s = 0..28 full pipeline ----
  for (int s = 0; s < 29; ++s) {
    STEP(s, 1, 1, "s_waitcnt vmcnt(2)");
  }
  // ---- tail ----
  STEP(29, 0, 1, "s_waitcnt vmcnt(0)");
  STEP(30, 0, 1, "s_waitcnt vmcnt(0)");
  STEP(31, 0, 0, "s_waitcnt vmcnt(0)");

  // ---- epilogue ----
  float b1r[8], ar[8];
#pragma unroll
  for (int ni = 0; ni < 8; ++ni) {
    const int c = wn * 128 + ni * 16 + fr;
    b1r[ni] = b1[c];
    ar[ni]  = aw[c];
  }
#pragma unroll
  for (int mi = 0; mi < 4; ++mi) {
#pragma unroll
    for (int r = 0; r < 4; ++r) {
      float sum = 0.f;
#pragma unroll
      for (int ni = 0; ni < 8; ++ni) {
        const float h = acc[mi][ni][r] + b1r[ni];
        sum += fmaxf(h, 0.f) * ar[ni];
      }
      sum += __shfl_xor(sum, 1);
      sum += __shfl_xor(sum, 2);
      sum += __shfl_xor(sum, 4);
      sum += __shfl_xor(sum, 8);
      if (fr == 0) {
        const int row = mi * 16 + kg * 4 + r;
        atomicAdd(&mlp_acc[row], sum);
      }
    }
  }
  if (wn == 0) {
#pragma unroll
    for (int mi = 0; mi < 4; ++mi) {
      lin[mi] += __shfl_xor(lin[mi], 16);
      lin[mi] += __shfl_xor(lin[mi], 32);
    }
    if (lane < 16) {
#pragma unroll
      for (int mi = 0; mi < 4; ++mi)
        lin_acc[mi * 16 + lane] = lin[mi];
    }
  }
  __syncthreads();
  if (t < BM)
    out[blockRow + t] = lin_acc[t] + mlp_acc[t] + b2p[0];
}

extern "C" void kernel_launch(void* const* d_in, const int* in_sizes, int n_in,
                              void* d_out, int out_size, void* d_ws, size_t ws_size,
                              hipStream_t stream) {
  const float* X     = (const float*)d_in[0];
  const float* y     = (const float*)d_in[1];
  const float* Xs    = (const float*)d_in[2];
  const float* gamma = (const float*)d_in[3];
  const float* W     = (const float*)d_in[4];
  const float* a     = (const float*)d_in[5];
  const float* b1    = (const float*)d_in[6];
  const float* b2    = (const float*)d_in[7];
  float* out = (float*)d_out;

  char* ws = (char*)d_ws;
  float*  v       = (float*)(ws + 0);
  float*  u1      = (float*)(ws + 4096);
  float*  u2      = (float*)(ws + 8192);
  float*  rep_lin = (float*)(ws + 12288);
  float*  repn    = (float*)(ws + 16384);
  ushort* WnF     = (ushort*)(ws + 20480);

  hipMemsetAsync(ws, 0, 3 * 4096, stream);
  hipLaunchKernelGGL(xty_kernel,     dim3(256), dim3(256), 0, stream, X, y, v);
  hipLaunchKernelGGL(xtxw_kernel,    dim3(256), dim3(256), 0, stream, X, v, u1);
  hipLaunchKernelGGL(xtxw_kernel,    dim3(256), dim3(256), 0, stream, X, u1, u2);
  hipLaunchKernelGGL(combine_kernel, dim3(1),   dim3(256), 0, stream, v, u1, u2, gamma, rep_lin, repn);
  hipLaunchKernelGGL(wn_frag_kernel, dim3(256), dim3(256), 0, stream, W, repn, WnF);
  hipLaunchKernelGGL(fused_kernel,   dim3(K_ROWS / BM), dim3(256), 0, stream,
                     Xs, WnF, rep_lin, b1, a, b2, out);
}

// Round 11
// 315.646 us; speedup vs baseline: 1.6943x; 1.0206x over previous
//
#include <hip/hip_runtime.h>
#include <hip/hip_bf16.h>
#include <stdint.h>

#define D_DIM 1024
#define P_ROWS 8192
#define K_ROWS 131072
#define M_DIM 512
#define L_STEPS 64
#define BM 64
#define XS_ROW_BYTES 4096

typedef short bf16x8_t __attribute__((ext_vector_type(8)));
typedef float f32x4_t __attribute__((ext_vector_type(4)));

typedef const __attribute__((address_space(1))) void* gas_t;
typedef __attribute__((address_space(3))) void* las_t;

__device__ __forceinline__ uint32_t f2bf(float f) {
  union { float f; uint32_t u; } c; c.f = f;
  const uint32_t u = c.u;
  return (u + 0x7FFFu + ((u >> 16) & 1u)) >> 16;   // RNE
}

__device__ __forceinline__ bf16x8_t as_bf16x8(uint4 v) {
  union { uint4 u; bf16x8_t h; } c; c.u = v; return c.h;
}

__device__ __forceinline__ bf16x8_t cvt_frag(const f32x4_t& a0, const f32x4_t& a1) {
  uint32_t p0, p1, p2, p3;
  asm("v_cvt_pk_bf16_f32 %0, %1, %2" : "=v"(p0) : "v"(a0[0]), "v"(a0[1]));
  asm("v_cvt_pk_bf16_f32 %0, %1, %2" : "=v"(p1) : "v"(a0[2]), "v"(a0[3]));
  asm("v_cvt_pk_bf16_f32 %0, %1, %2" : "=v"(p2) : "v"(a1[0]), "v"(a1[1]));
  asm("v_cvt_pk_bf16_f32 %0, %1, %2" : "=v"(p3) : "v"(a1[2]), "v"(a1[3]));
  union { uint32_t u[4]; bf16x8_t h; } c;
  c.u[0] = p0; c.u[1] = p1; c.u[2] = p2; c.u[3] = p3;
  return c.h;
}

// v[d] += sum_i y[i] * X[i,d]
__global__ void xty_kernel(const float* __restrict__ X, const float* __restrict__ y,
                           float* __restrict__ v) {
  const int d0 = threadIdx.x * 4;
  float a0 = 0.f, a1 = 0.f, a2 = 0.f, a3 = 0.f;
  for (int i = blockIdx.x; i < P_ROWS; i += gridDim.x) {
    const float s = y[i];
    const float4 x = *reinterpret_cast<const float4*>(X + (size_t)i * D_DIM + d0);
    a0 += s * x.x; a1 += s * x.y; a2 += s * x.z; a3 += s * x.w;
  }
  atomicAdd(v + d0 + 0, a0);
  atomicAdd(v + d0 + 1, a1);
  atomicAdd(v + d0 + 2, a2);
  atomicAdd(v + d0 + 3, a3);
}

// wout[d] += sum_i (X[i,:].win) * X[i,d]
__global__ void xtxw_kernel(const float* __restrict__ X, const float* __restrict__ win,
                            float* __restrict__ wout) {
  __shared__ float red[4][D_DIM];
  const int lane = threadIdx.x & 63;
  const int wave = threadIdx.x >> 6;
  const int gw = blockIdx.x * 4 + wave;
  const int nw = gridDim.x * 4;
  float wv[16], acc[16];
#pragma unroll
  for (int q = 0; q < 4; ++q) {
    const float4 tv = *reinterpret_cast<const float4*>(win + q * 256 + lane * 4);
    wv[q*4+0] = tv.x; wv[q*4+1] = tv.y; wv[q*4+2] = tv.z; wv[q*4+3] = tv.w;
  }
#pragma unroll
  for (int j = 0; j < 16; ++j) acc[j] = 0.f;
  for (int i = gw; i < P_ROWS; i += nw) {
    const float* xr = X + (size_t)i * D_DIM;
    float xv[16];
    float dot = 0.f;
#pragma unroll
    for (int q = 0; q < 4; ++q) {
      const float4 tv = *reinterpret_cast<const float4*>(xr + q * 256 + lane * 4);
      xv[q*4+0] = tv.x; xv[q*4+1] = tv.y; xv[q*4+2] = tv.z; xv[q*4+3] = tv.w;
      dot += tv.x * wv[q*4+0] + tv.y * wv[q*4+1] + tv.z * wv[q*4+2] + tv.w * wv[q*4+3];
    }
#pragma unroll
    for (int m = 1; m < 64; m <<= 1) dot += __shfl_xor(dot, m);
#pragma unroll
    for (int j = 0; j < 16; ++j) acc[j] += dot * xv[j];
  }
#pragma unroll
  for (int q = 0; q < 4; ++q) {
    float4 tv;
    tv.x = acc[q*4+0]; tv.y = acc[q*4+1]; tv.z = acc[q*4+2]; tv.w = acc[q*4+3];
    *reinterpret_cast<float4*>(&red[wave][q * 256 + lane * 4]) = tv;
  }
  __syncthreads();
  const int d0 = threadIdx.x * 4;
#pragma unroll
  for (int j = 0; j < 4; ++j)
    atomicAdd(wout + d0 + j, red[0][d0+j] + red[1][d0+j] + red[2][d0+j] + red[3][d0+j]);
}

// rep = gamma*(64 v - 2016 eps u1/P + 41664 eps^2 u2/P^2); emit rep/(L*P) and rep/||rep||
__global__ void combine_kernel(const float* __restrict__ v, const float* __restrict__ u1,
                               const float* __restrict__ u2, const float* __restrict__ gamma_p,
                               float* __restrict__ rep_lin, float* __restrict__ repn) {
  __shared__ float sred[4];
  const float gamma = *gamma_p;
  const float eps = gamma / (float)L_STEPS;
  const float c1 = 2016.0f * eps / (float)P_ROWS;
  const float c2 = 41664.0f * eps * eps / ((float)P_ROWS * (float)P_ROWS);
  const int d0 = threadIdx.x * 4;
  float r[4];
  float ss = 0.f;
#pragma unroll
  for (int j = 0; j < 4; ++j) {
    const float val = gamma * ((float)L_STEPS * v[d0+j] - c1 * u1[d0+j] + c2 * u2[d0+j]);
    r[j] = val;
    ss += val * val;
  }
#pragma unroll
  for (int m = 1; m < 64; m <<= 1) ss += __shfl_xor(ss, m);
  if ((threadIdx.x & 63) == 0) sred[threadIdx.x >> 6] = ss;
  __syncthreads();
  const float norm = sqrtf(sred[0] + sred[1] + sred[2] + sred[3]);
  const float inv_norm = 1.0f / (norm + 1e-8f);
  const float lin_s = 1.0f / ((float)L_STEPS * (float)P_ROWS);
#pragma unroll
  for (int j = 0; j < 4; ++j) {
    rep_lin[d0+j] = r[j] * lin_s;
    repn[d0+j]    = r[j] * inv_norm;
  }
}

// WnF fragment-major: byte addr (s*32+f)*1024 + l*16 holds bf16 x8 of
// W[f*16+(l&15)][s*32+(l>>4)*8 + 0..7] * repn[...]
__global__ void wn_frag_kernel(const float* __restrict__ W, const float* __restrict__ repn,
                               ushort* __restrict__ WnF) {
  const int gid = blockIdx.x * 256 + threadIdx.x;   // 65536
  const int l = gid & 63;
  const int f = (gid >> 6) & 31;
  const int s = gid >> 11;
  const int m = f * 16 + (l & 15);
  const int d0 = s * 32 + ((l >> 4) << 3);
  const float4 w0 = *reinterpret_cast<const float4*>(W + (size_t)m * D_DIM + d0);
  const float4 w1 = *reinterpret_cast<const float4*>(W + (size_t)m * D_DIM + d0 + 4);
  const float4 r0 = *reinterpret_cast<const float4*>(repn + d0);
  const float4 r1 = *reinterpret_cast<const float4*>(repn + d0 + 4);
  uint4 o;
  o.x = f2bf(w0.x*r0.x) | (f2bf(w0.y*r0.y) << 16);
  o.y = f2bf(w0.z*r0.z) | (f2bf(w0.w*r0.w) << 16);
  o.z = f2bf(w1.x*r1.x) | (f2bf(w1.y*r1.y) << 16);
  o.w = f2bf(w1.z*r1.z) | (f2bf(w1.w*r1.w) << 16);
  *reinterpret_cast<uint4*>(WnF + (size_t)gid * 8) = o;
}

// Fused GEMM, round 11: occupancy over per-wave pipelining.
// BM=64, BN=512(full), 512 threads = 8 waves, wave tile 64x64 (4 m x 4 n frags),
// acc = 64 AGPR -> ~120 VGPR total -> 4 waves/SIMD (2 blocks x 8 waves / CU).
// In-order vmcnt means B-waits collapse deep A-prefetch (rounds 5-10 lesson);
// with 16 waves/CU the latency is hidden by OTHER waves instead.
// Per wave/step: 1 A-DMA (1KB), 4 B-loads (L2), 8 ds_read b128 (swizzled), 16 MFMA.
// vmcnt(1): newer-than-B(s) = stage(s+3) only.
#define STEP(SC, DO_STAGE, DO_PFB, WSTR) do {                                    \
    if (DO_STAGE) stage((SC) + 3);                                               \
    const char* Ab = &Abuf[0][0] + ((SC) & 3) * 8192;                            \
    bf16x8_t afr[4];                                                             \
    _Pragma("unroll")                                                            \
    for (int mi = 0; mi < 4; ++mi) {                                             \
      const f32x4_t va = *reinterpret_cast<const f32x4_t*>(Ab + aoff0 + mi * 2048); \
      const f32x4_t vb = *reinterpret_cast<const f32x4_t*>(Ab + aoff1 + mi * 2048); \
      if (wn == 0) {                                                             \
        const f32x4_t rp0 = *reinterpret_cast<const f32x4_t*>((const char*)repl + (SC) * 128 + roff);      \
        const f32x4_t rp1 = *reinterpret_cast<const f32x4_t*>((const char*)repl + (SC) * 128 + roff + 16); \
        lin[mi] += va[0]*rp0[0] + va[1]*rp0[1] + va[2]*rp0[2] + va[3]*rp0[3]     \
                 + vb[0]*rp1[0] + vb[1]*rp1[1] + vb[2]*rp1[2] + vb[3]*rp1[3];    \
      }                                                                          \
      afr[mi] = cvt_frag(va, vb);                                                \
    }                                                                            \
    __builtin_amdgcn_sched_barrier(0);                                           \
    asm volatile(WSTR ::: "memory");                                             \
    __builtin_amdgcn_sched_barrier(0);                                           \
    __builtin_amdgcn_s_setprio(1);                                               \
    _Pragma("unroll")                                                            \
    for (int mi = 0; mi < 4; ++mi)                                               \
      _Pragma("unroll")                                                          \
      for (int ni = 0; ni < 4; ++ni)                                             \
        acc[mi][ni] = __builtin_amdgcn_mfma_f32_16x16x32_bf16(afr[mi], as_bf16x8(Bv[ni]), acc[mi][ni], 0, 0, 0); \
    __builtin_amdgcn_s_setprio(0);                                               \
    __builtin_amdgcn_sched_barrier(0);                                           \
    if (DO_PFB) {                                                                \
      _Pragma("unroll")                                                          \
      for (int ni = 0; ni < 4; ++ni)                                             \
        Bv[ni] = *reinterpret_cast<const uint4*>(gB + (size_t)((SC) + 1) * 32768 + ni * 1024); \
    }                                                                            \
    __builtin_amdgcn_sched_barrier(0);                                           \
    __builtin_amdgcn_s_barrier();                                                \
    __builtin_amdgcn_sched_barrier(0);                                           \
  } while (0)

__global__ __launch_bounds__(512, 4)
void fused_kernel(const float* __restrict__ Xs, const ushort* __restrict__ WnF,
                  const float* __restrict__ rep_lin, const float* __restrict__ b1,
                  const float* __restrict__ aw, const float* __restrict__ b2p,
                  float* __restrict__ out) {
  __shared__ __align__(16) char Abuf[4][8192];     // 32 KB, f32 A tiles (swizzled)
  __shared__ __align__(16) float repl[D_DIM];      // 4 KB
  __shared__ float mlp_acc[BM];
  __shared__ float lin_acc[BM];

  const int t = threadIdx.x;
  const int lane = t & 63;
  const int wn = t >> 6;       // 0..7 (wave id == N-slice of 64 cols)
  const int fr = lane & 15;
  const int kg = lane >> 4;
  const size_t blockRow = (size_t)blockIdx.x * BM;

  // --- DMA staging: 1 instr/wave; lane-linear LDS dst, pre-swizzled global src ---
  const int sr = wn * 8 + (lane >> 3);             // rows 0..63
  const char* gA = (const char*)Xs + (blockRow + (size_t)sr) * XS_ROW_BYTES
                 + (size_t)(((lane & 7) ^ (sr & 7)) * 16);

  // B: fragment-major; wave wn covers n-frags 4*wn .. 4*wn+3
  const char* gB = (const char*)WnF + (size_t)wn * 4096 + (size_t)lane * 16;

  // --- swizzled ds_read offsets for A frags (row = fr + mi*16) ---
  const int fs = fr & 7;
  const int aoff0 = fr * 128 + (((kg * 2)     ^ fs) * 16);   // + mi*2048
  const int aoff1 = fr * 128 + (((kg * 2 + 1) ^ fs) * 16);
  const int roff = kg * 32;                                  // + s*128

  auto stage = [&](int tile) {
    char* d0 = &Abuf[0][0] + (size_t)((tile & 3) * 8192 + wn * 1024);
    __builtin_amdgcn_global_load_lds((gas_t)(gA + (size_t)tile * 128), (las_t)d0, 16, 0, 0);
  };

  f32x4_t acc[4][4];
#pragma unroll
  for (int mi = 0; mi < 4; ++mi)
#pragma unroll
    for (int ni = 0; ni < 4; ++ni)
      acc[mi][ni] = f32x4_t{0.f, 0.f, 0.f, 0.f};
  float lin[4] = {0.f, 0.f, 0.f, 0.f};
  uint4 Bv[4];

  // ---- prologue: A(0..2) DMA, B(0) ----
  if (t < BM) mlp_acc[t] = 0.f;
  *reinterpret_cast<float2*>(&repl[t * 2]) = *reinterpret_cast<const float2*>(rep_lin + t * 2);
  stage(0); stage(1); stage(2);
#pragma unroll
  for (int ni = 0; ni < 4; ++ni)
    Bv[ni] = *reinterpret_cast<const uint4*>(gB + ni * 1024);
  asm volatile("s_waitcnt vmcnt(0)" ::: "memory");
  __syncthreads();

  // ---- main loop: s = 0..28 full pipeline ----
  for (int s = 0; s < 29; ++s) {
    STEP(s, 1, 1, "s_waitcnt vmcnt(1)");
  }
  // ---- tail ----
  STEP(29, 0, 1, "s_waitcnt vmcnt(0)");
  STEP(30, 0, 1, "s_waitcnt vmcnt(0)");
  STEP(31, 0, 0, "s_waitcnt vmcnt(0)");

  // ---- epilogue ----
  float b1r[4], ar[4];
#pragma unroll
  for (int ni = 0; ni < 4; ++ni) {
    const int c = wn * 64 + ni * 16 + fr;
    b1r[ni] = b1[c];
    ar[ni]  = aw[c];
  }
#pragma unroll
  for (int mi = 0; mi < 4; ++mi) {
#pragma unroll
    for (int r = 0; r < 4; ++r) {
      float sum = 0.f;
#pragma unroll
      for (int ni = 0; ni < 4; ++ni) {
        const float h = acc[mi][ni][r] + b1r[ni];
        sum += fmaxf(h, 0.f) * ar[ni];
      }
      sum += __shfl_xor(sum, 1);
      sum += __shfl_xor(sum, 2);
      sum += __shfl_xor(sum, 4);
      sum += __shfl_xor(sum, 8);
      if (fr == 0) {
        const int row = mi * 16 + kg * 4 + r;
        atomicAdd(&mlp_acc[row], sum);
      }
    }
  }
  if (wn == 0) {
#pragma unroll
    for (int mi = 0; mi < 4; ++mi) {
      lin[mi] += __shfl_xor(lin[mi], 16);
      lin[mi] += __shfl_xor(lin[mi], 32);
    }
    if (lane < 16) {
#pragma unroll
      for (int mi = 0; mi < 4; ++mi)
        lin_acc[mi * 16 + lane] = lin[mi];
    }
  }
  __syncthreads();
  if (t < BM)
    out[blockRow + t] = lin_acc[t] + mlp_acc[t] + b2p[0];
}

extern "C" void kernel_launch(void* const* d_in, const int* in_sizes, int n_in,
                              void* d_out, int out_size, void* d_ws, size_t ws_size,
                              hipStream_t stream) {
  const float* X     = (const float*)d_in[0];
  const float* y     = (const float*)d_in[1];
  const float* Xs    = (const float*)d_in[2];
  const float* gamma = (const float*)d_in[3];
  const float* W     = (const float*)d_in[4];
  const float* a     = (const float*)d_in[5];
  const float* b1    = (const float*)d_in[6];
  const float* b2    = (const float*)d_in[7];
  float* out = (float*)d_out;

  char* ws = (char*)d_ws;
  float*  v       = (float*)(ws + 0);
  float*  u1      = (float*)(ws + 4096);
  float*  u2      = (float*)(ws + 8192);
  float*  rep_lin = (float*)(ws + 12288);
  float*  repn    = (float*)(ws + 16384);
  ushort* WnF     = (ushort*)(ws + 20480);

  hipMemsetAsync(ws, 0, 3 * 4096, stream);
  hipLaunchKernelGGL(xty_kernel,     dim3(256), dim3(256), 0, stream, X, y, v);
  hipLaunchKernelGGL(xtxw_kernel,    dim3(256), dim3(256), 0, stream, X, v, u1);
  hipLaunchKernelGGL(xtxw_kernel,    dim3(256), dim3(256), 0, stream, X, u1, u2);
  hipLaunchKernelGGL(combine_kernel, dim3(1),   dim3(256), 0, stream, v, u1, u2, gamma, rep_lin, repn);
  hipLaunchKernelGGL(wn_frag_kernel, dim3(256), dim3(256), 0, stream, W, repn, WnF);
  hipLaunchKernelGGL(fused_kernel,   dim3(K_ROWS / BM), dim3(512), 0, stream,
                     Xs, WnF, rep_lin, b1, a, b2, out);
}